// Round 8
// baseline (412.286 us; speedup 1.0000x reference)
//
#include <hip/hip_runtime.h>
#include <math.h>

// SNN forward, fused per batch element. Inputs f32, output f32 [2048][200].
// R8: BARRIER-FREE inner loops. Each wave owns C-cols [32w,32w+32): it runs
// the GEMM for those cols AND the membrane scan for them (lanes 0-31 <-> cols,
// wave-local sc scratch, same-wave lgkm ordering -> no __syncthreads per tile).
// Spike bits ping-pong between two LDS buffers; ONE barrier per layer.
// Spikes expand to bf16 MFMA A-frags in VGPRs (mul-spread trick, R7).
// 512 thr / 8 waves / 2 blocks/CU.

#define T_N 150
#define DIN 20
#define H 256
#define NOUT 200
#define NMT 10
#define CST 20           // sc col stride (f32): 16 rows + 4 pad, 16B-aligned
#define SCB 5120         // sc buffer stride (f32) = 256 cols * CST
#define XAP 40           // xa row stride (bf16)
#define BW 12            // bits row stride (dwords)

#define WS_W1 0
#define WS_W2 5120
#define WS_W3 70656
#define WS_W4 136192
#define WS_WO 201728
#define WS_TOT 252928

typedef short s16x8 __attribute__((ext_vector_type(8)));
typedef float f32x4 __attribute__((ext_vector_type(4)));
typedef unsigned int u32x4 __attribute__((ext_vector_type(4)));

__device__ __forceinline__ unsigned short f2bf(float f) {
  union { float f; unsigned int i; } v; v.f = f;
  unsigned int r = v.i + 0x7FFFu + ((v.i >> 16) & 1u);
  return (unsigned short)(r >> 16);
}

__global__ void cvt_weights(const float* __restrict__ W1, const float* __restrict__ W2,
                            const float* __restrict__ W3, const float* __restrict__ W4,
                            const float* __restrict__ Wo, unsigned short* __restrict__ ws) {
  int idx = blockIdx.x * blockDim.x + threadIdx.x;
  int stride = gridDim.x * blockDim.x;
  for (int i = idx; i < WS_TOT; i += stride) {
    float v;
    if (i < WS_W2)      v = W1[i - WS_W1];
    else if (i < WS_W3) v = W2[i - WS_W2];
    else if (i < WS_W4) v = W3[i - WS_W3];
    else if (i < WS_WO) v = W4[i - WS_W4];
    else                v = Wo[i - WS_WO];
    ws[i] = f2bf(v);
  }
}

// expand 8 spike bits (byte t) -> packed-bf16 x8 fragment (0.0 / 1.0)
__device__ __forceinline__ s16x8 expand8(unsigned int t) {
  unsigned int r2 = t * 0x8001u;   // bit 2j -> pos 2j ; bit 2j+1 -> pos 16+2j
  u32x4 d;
  d[0] = (r2 & 0x00010001u) * 0x3F80u;
  d[1] = (r2 & 0x00040004u) * 0x0FE0u;
  d[2] = (r2 & 0x00100010u) * 0x03F8u;
  d[3] = (r2 & 0x00400040u) * 0x00FEu;
  union { u32x4 u; s16x8 s; } cv; cv.u = d;
  return cv.s;
}

__global__ __launch_bounds__(512, 4) void snn_fused(
    const float* __restrict__ x,             // [2048][150][20] f32
    const unsigned short* __restrict__ wsb,  // bf16 weights (d_ws)
    const float* __restrict__ b1,            // [256] f32
    const float* __restrict__ b2,
    const float* __restrict__ b3,
    const float* __restrict__ b4,
    float* __restrict__ out)                 // [2048][200] f32
{
  __shared__ float sc[2 * SCB];              // 40960 B: col-major C scratch (dbuf)
  __shared__ unsigned int bits[2][160 * BW]; // 15360 B: spike bits, ping-pong
  __shared__ unsigned short xa[160 * XAP];   // 12800 B: padded bf16 x (layer 1)
                                             // total 69120 B -> 2 blocks/CU

  const int tid  = threadIdx.x;
  const int lane = tid & 63;
  const int wave = tid >> 6;    // 0..7
  const int c16  = lane & 15;   // MFMA: A row m / B col n / C col
  const int quad = lane >> 4;
  const int shq  = quad * 8;    // bit shift for this lane's mask byte
  const int bidx = blockIdx.x;
  const int col0 = 32 * wave + c16;       // wave owns cols [32w, 32w+32)
  const int col1 = col0 + 16;
  const int scol = lane & 31;             // scan: lane -> wave-local col

  // C-store: wave-local region of sc (cols 32w..32w+31), col-major
  auto store_c = [&](int sb, f32x4 c0, f32x4 c1) {
    *(f32x4*)&sc[sb * SCB + col0 * CST + quad * 4] = c0;
    *(f32x4*)&sc[sb * SCB + col1 * CST + quad * 4] = c1;
  };

  // membrane scan of tile mt: lanes 0-31 own the wave's 32 cols; same-wave
  // data only (no barrier). Ballot low-32 = this wave's col-group mask.
  auto scan_tile = [&](int mt, int sb, float& m, unsigned int* wbits) {
    const f32x4* vp = (const f32x4*)&sc[sb * SCB + (32 * wave + scol) * CST];
    f32x4 v[4];
    #pragma unroll
    for (int j = 0; j < 4; ++j) v[j] = vp[j];
    unsigned int keep = 0;
    #pragma unroll
    for (int r = 0; r < 16; ++r) {
      int t = mt * 16 + r;
      if (t < T_N) {  // block-uniform
        float inp = v[r >> 2][r & 3];            // bias folded into C-init
        float sel = (m > 1.0f) ? (inp - 1.0f) : inp;
        m = 0.9f * m + sel;
        unsigned long long msk = __ballot(m > 1.0f);
        if (lane == r) keep = (unsigned int)msk;
      }
    }
    if (lane < 16) wbits[(mt * 16 + lane) * BW + wave] = keep;
  };

  // ---- init: zero xa pads; stage x as bf16 ----
  for (int i = tid; i < (160 * XAP) / 2; i += 512) ((unsigned int*)xa)[i] = 0;
  __syncthreads();
  const float* xb = x + (size_t)bidx * (T_N * DIN);
  for (int e = tid; e < T_N * DIN; e += 512) {
    int t = e / DIN;
    int i = e - t * DIN;
    xa[t * XAP + i] = f2bf(xb[e]);
  }

  // ---- layer 1: x @ W1^T (K=20 pad 32) -> bits[0]; no intra-layer barrier ----
  {
    s16x8 w1f[2];
    #pragma unroll
    for (int i = 0; i < 2; ++i) {
      int n = (i == 0) ? col0 : col1;
      #pragma unroll
      for (int j = 0; j < 8; ++j) {
        int k = shq + j;
        w1f[i][j] = (k < DIN) ? (short)wsb[WS_W1 + n * DIN + k] : (short)0;
      }
      asm volatile("" : "+v"(w1f[i]));
    }
    float bc0 = b1[col0], bc1 = b1[col1];
    float m = 0.0f;
    __syncthreads();  // xa staged
    for (int mt = 0; mt < NMT; ++mt) {
      const s16x8 a1 = *(const s16x8*)&xa[(mt * 16 + c16) * XAP + shq];
      f32x4 c0 = {bc0, bc0, bc0, bc0};
      f32x4 c1 = {bc1, bc1, bc1, bc1};
      c0 = __builtin_amdgcn_mfma_f32_16x16x32_bf16(a1, w1f[0], c0, 0, 0, 0);
      c1 = __builtin_amdgcn_mfma_f32_16x16x32_bf16(a1, w1f[1], c1, 0, 0, 0);
      if (mt > 0) scan_tile(mt - 1, (mt - 1) & 1, m, bits[0]);
      store_c(mt & 1, c0, c1);
    }
    scan_tile(9, 1, m, bits[0]);
  }
  __syncthreads();  // phase barrier: bits[0] complete

  // ---- layers 2..4: barrier-free tile loop; bits ping-pong ----
  const float* bsl[3] = {b2, b3, b4};
  const int wofs[3] = {WS_W2, WS_W3, WS_W4};
  for (int l = 0; l < 3; ++l) {
    const unsigned short* wl = wsb + wofs[l];
    const unsigned int* rbits = bits[l & 1];
    unsigned int* wbits = bits[(l & 1) ^ 1];
    s16x8 wf0[8], wf1[8];
    #pragma unroll
    for (int ks = 0; ks < 8; ++ks) {
      wf0[ks] = *(const s16x8*)(wl + col0 * H + ks * 32 + shq);
      wf1[ks] = *(const s16x8*)(wl + col1 * H + ks * 32 + shq);
      asm volatile("" : "+v"(wf0[ks]));
      asm volatile("" : "+v"(wf1[ks]));
    }
    float bc0 = bsl[l][col0], bc1 = bsl[l][col1];
    float m = 0.0f;
    for (int mt = 0; mt < NMT; ++mt) {
      const unsigned int* bp = &rbits[(mt * 16 + c16) * BW];
      u32x4 rm0 = *(const u32x4*)bp;
      u32x4 rm1 = *(const u32x4*)(bp + 4);
      unsigned int rm[8] = {rm0[0], rm0[1], rm0[2], rm0[3],
                            rm1[0], rm1[1], rm1[2], rm1[3]};
      f32x4 c0 = {bc0, bc0, bc0, bc0};
      f32x4 c1 = {bc1, bc1, bc1, bc1};
      #pragma unroll
      for (int ks = 0; ks < 8; ++ks) {
        s16x8 a = expand8((rm[ks] >> shq) & 0xFFu);
        c0 = __builtin_amdgcn_mfma_f32_16x16x32_bf16(a, wf0[ks], c0, 0, 0, 0);
        c1 = __builtin_amdgcn_mfma_f32_16x16x32_bf16(a, wf1[ks], c1, 0, 0, 0);
      }
      if (mt > 0) scan_tile(mt - 1, (mt - 1) & 1, m, wbits);
      store_c(mt & 1, c0, c1);
    }
    scan_tile(9, 1, m, wbits);
    __syncthreads();  // phase barrier: wbits complete
  }

  // ---- output layer (reads bits[1]): GEMM + mo-scan + softmax (t > 50) ----
  {
    s16x8 wo0[8], wo1[8];
    #pragma unroll
    for (int ks = 0; ks < 8; ++ks) {
      s16x8 z = {0, 0, 0, 0, 0, 0, 0, 0};
      wo0[ks] = (col0 < NOUT) ? *(const s16x8*)(wsb + WS_WO + col0 * H + ks * 32 + shq) : z;
      wo1[ks] = (col1 < NOUT) ? *(const s16x8*)(wsb + WS_WO + col1 * H + ks * 32 + shq) : z;
      asm volatile("" : "+v"(wo0[ks]));
      asm volatile("" : "+v"(wo1[ks]));
    }

    float mo = 0.0f;
    float a0 = 0.f, a1 = 0.f, a2 = 0.f, a3 = 0.f;

    auto moscan = [&](int mt, int sb) {
      if (tid < 208) {
        f32x4* vp = (f32x4*)&sc[sb * SCB + tid * CST];
        f32x4 v[4];
        #pragma unroll
        for (int j = 0; j < 4; ++j) v[j] = vp[j];
        #pragma unroll
        for (int r = 0; r < 16; ++r) {
          int t = mt * 16 + r;
          if (t < T_N) {
            float reset = (mo > 1.0f) ? 1.0f : 0.0f;
            mo = 0.9f * mo + v[r / 4][r % 4] - reset;
            v[r / 4][r % 4] = mo;
          }
        }
        #pragma unroll
        for (int j = 0; j < 4; ++j) vp[j] = v[j];
      }
    };
    auto softmax_t = [&](int mt, int sb) {
      #pragma unroll
      for (int rr = 0; rr < 2; ++rr) {
        int r = 2 * wave + rr;
        int t = mt * 16 + r;
        if (t > 50 && t < T_N) {        // wave-uniform
          const float* sb_p = &sc[sb * SCB + r];
          float v0 = sb_p[lane * CST];
          float v1 = sb_p[(64 + lane) * CST];
          float v2 = sb_p[(128 + lane) * CST];
          bool has3 = (lane < 8);        // n=192+lane valid only for n<200
          float v3 = has3 ? sb_p[(192 + lane) * CST] : -INFINITY;
          float mx = fmaxf(fmaxf(v0, v1), fmaxf(v2, v3));
          #pragma unroll
          for (int d = 32; d >= 1; d >>= 1) mx = fmaxf(mx, __shfl_xor(mx, d));
          float e0 = __expf(v0 - mx), e1 = __expf(v1 - mx), e2 = __expf(v2 - mx);
          float e3 = has3 ? __expf(v3 - mx) : 0.0f;
          float s = e0 + e1 + e2 + e3;
          #pragma unroll
          for (int d = 32; d >= 1; d >>= 1) s += __shfl_xor(s, d);
          float inv = 1.0f / s;
          a0 += e0 * inv; a1 += e1 * inv; a2 += e2 * inv; a3 += e3 * inv;
        }
      }
    };

    for (int mt = 0; mt < NMT; ++mt) {
      const unsigned int* bp = &bits[1][(mt * 16 + c16) * BW];
      u32x4 rm0 = *(const u32x4*)bp;
      u32x4 rm1 = *(const u32x4*)(bp + 4);
      unsigned int rm[8] = {rm0[0], rm0[1], rm0[2], rm0[3],
                            rm1[0], rm1[1], rm1[2], rm1[3]};
      f32x4 c0 = {0.f, 0.f, 0.f, 0.f};
      f32x4 c1 = {0.f, 0.f, 0.f, 0.f};
      #pragma unroll
      for (int ks = 0; ks < 8; ++ks) {
        s16x8 a = expand8((rm[ks] >> shq) & 0xFFu);
        c0 = __builtin_amdgcn_mfma_f32_16x16x32_bf16(a, wo0[ks], c0, 0, 0, 0);
        c1 = __builtin_amdgcn_mfma_f32_16x16x32_bf16(a, wo1[ks], c1, 0, 0, 0);
      }
      if (mt > 0) moscan(mt - 1, (mt - 1) & 1);
      store_c(mt & 1, c0, c1);
      __syncthreads();
      if (mt > 0) { softmax_t(mt - 1, (mt - 1) & 1); __syncthreads(); }
    }
    moscan(9, 1);  __syncthreads();
    softmax_t(9, 1); __syncthreads();

    // merge 8 per-wave accumulators (sc reused flat), store f32
    sc[wave * 260 + lane]       = a0;
    sc[wave * 260 + 64 + lane]  = a1;
    sc[wave * 260 + 128 + lane] = a2;
    if (lane < 8) sc[wave * 260 + 192 + lane] = a3;
    __syncthreads();
    if (tid < NOUT) {
      float v = 0.f;
      #pragma unroll
      for (int w = 0; w < 8; ++w) v += sc[w * 260 + tid];
      out[(size_t)bidx * NOUT + tid] = v;
    }
  }
}

extern "C" void kernel_launch(void* const* d_in, const int* in_sizes, int n_in,
                              void* d_out, int out_size, void* d_ws, size_t ws_size,
                              hipStream_t stream) {
  (void)in_sizes; (void)n_in; (void)ws_size; (void)out_size;
  unsigned short* wsb = (unsigned short*)d_ws;
  cvt_weights<<<256, 256, 0, stream>>>(
      (const float*)d_in[1], (const float*)d_in[3], (const float*)d_in[5],
      (const float*)d_in[7], (const float*)d_in[9], wsb);
  snn_fused<<<2048, 512, 0, stream>>>(
      (const float*)d_in[0], wsb,
      (const float*)d_in[2], (const float*)d_in[4],
      (const float*)d_in[6], (const float*)d_in[8],
      (float*)d_out);
}